// Round 12
// baseline (95.122 us; speedup 1.0000x reference)
//
#include <hip/hip_runtime.h>

#ifndef __has_builtin
#define __has_builtin(x) 0
#endif

#if __has_builtin(__builtin_amdgcn_logf)
__device__ __forceinline__ float flog2(float x) { return __builtin_amdgcn_logf(x); }
#else
__device__ __forceinline__ float flog2(float x) { return log2f(x); }
#endif
#if __has_builtin(__builtin_amdgcn_exp2f)
__device__ __forceinline__ float fexp2(float x) { return __builtin_amdgcn_exp2f(x); }
#else
__device__ __forceinline__ float fexp2(float x) { return exp2f(x); }
#endif

#define L2E 1.4426950408889634f   // log2(e)
#define LN2 0.6931471805599453
#define BIGL (1.0e10f * L2E)
#define CHUNKS 32                 // 32 chunks x 8 diag-pairs = 256 pairs

template <int CTRL, int RM, int BM>
__device__ __forceinline__ float dpp_f(float v, float old) {
  int r = __builtin_amdgcn_update_dpp(__builtin_bit_cast(int, old),
                                      __builtin_bit_cast(int, v),
                                      CTRL, RM, BM, false);
  return __builtin_bit_cast(float, r);
}

// lane i <- lane i-1; lane 0 <- 0. fp64 via DPP on both halves.
__device__ __forceinline__ double shup1z_d(double v) {
  int lo = __double2loint(v), hi = __double2hiint(v);
  int lo2 = __builtin_amdgcn_update_dpp(0, lo, 0x138, 0xF, 0xF, false);
  int hi2 = __builtin_amdgcn_update_dpp(0, hi, 0x138, 0xF, 0xF, false);
  return __hiloint2double(hi2, lo2);
}

// wave max -> lane 63 (nonnegative floats)
__device__ __forceinline__ float wave_max63(float m) {
  m = fmaxf(m, dpp_f<0x111, 0xF, 0xF>(m, m));  // row_shr:1
  m = fmaxf(m, dpp_f<0x112, 0xF, 0xF>(m, m));  // row_shr:2
  m = fmaxf(m, dpp_f<0x114, 0xF, 0xF>(m, m));  // row_shr:4
  m = fmaxf(m, dpp_f<0x118, 0xF, 0xF>(m, m));  // row_shr:8
  m = fmaxf(m, dpp_f<0x142, 0xA, 0xF>(m, m));  // row_bcast15 -> rows 1,3
  m = fmaxf(m, dpp_f<0x143, 0xC, 0xF>(m, m));  // row_bcast31 -> rows 2,3
  return m;
}

// ---------------- FUSED: waves 1-3 produce K chunks, wave 0 runs the DP ----
// One block per batch, 256 threads. Producers write K (bf16, pair-major) to
// global d_ws and set an LDS flag per chunk (store -> vmcnt(0) -> flag).
// Consumer = R9's verified f64 common-scale DP, polling the flag before each
// chunk's loads. Same-CU write/read => same-XCD L2; values deterministic so
// replay-stale L1 lines are value-identical.
__global__ __launch_bounds__(256) void softdtw_fused(
    const float* __restrict__ x, const float* __restrict__ y,
    uint4* __restrict__ Kp4g, float* __restrict__ out)
{
  const int b   = blockIdx.x;
  const int tid = threadIdx.x;
  const int wid = tid >> 6;
  const int t   = tid & 63;

  __shared__ int flags[CHUNKS];
  if (tid < CHUNKS) flags[tid] = 0;
  __syncthreads();
  volatile int* vflags = flags;

  uint4* kp = Kp4g + (size_t)b * 16384;   // 256 pairs x 64 lanes

  if (wid != 0) {
    // ------------- producers (waves 1..3) -------------
    const float* xb = x + (size_t)b * 2048;
    const float* yb = y + (size_t)b * 2048;
    float4 xr[8];   // x rows 4t..4t+3 (2 float4 each) in VGPRs
    #pragma unroll
    for (int r = 0; r < 4; ++r) {
      xr[2 * r]     = *(const float4*)(xb + (4 * t + r) * 8);
      xr[2 * r + 1] = *(const float4*)(xb + (4 * t + r) * 8 + 4);
    }
    for (int c = wid - 1; c < CHUNKS; c += 3) {
      #pragma unroll 1
      for (int q = 0; q < 8; ++q) {
        int p = c * 8 + q;             // pair index
        unsigned w0, w1, w2, w3;
        unsigned hw[4];
        #pragma unroll
        for (int h = 0; h < 2; ++h) {
          int kk = 2 * p + h;
          #pragma unroll
          for (int r = 0; r < 4; ++r) {
            int i0 = 4 * t + r;
            int j0 = kk - i0;
            bool valid = (unsigned)j0 < 256u;
            int jc = j0 < 0 ? 0 : (j0 > 255 ? 255 : j0);
            float4 ya = *(const float4*)(yb + jc * 8);
            float4 yc = *(const float4*)(yb + jc * 8 + 4);
            float d, D;
            d = xr[2*r].x   - ya.x; D = d * d;
            d = xr[2*r].y   - ya.y; D = fmaf(d, d, D);
            d = xr[2*r].z   - ya.z; D = fmaf(d, d, D);
            d = xr[2*r].w   - ya.w; D = fmaf(d, d, D);
            d = xr[2*r+1].x - yc.x; D = fmaf(d, d, D);
            d = xr[2*r+1].y - yc.y; D = fmaf(d, d, D);
            d = xr[2*r+1].z - yc.z; D = fmaf(d, d, D);
            d = xr[2*r+1].w - yc.w; D = fmaf(d, d, D);
            float K = valid ? fexp2(-L2E * D) : 0.0f;
            unsigned kb = __builtin_bit_cast(unsigned, K);
            hw[r] = (kb + 0x7FFFu + ((kb >> 16) & 1u)) >> 16;   // RNE bf16
          }
          if (h == 0) { w0 = hw[0] | (hw[1] << 16); w1 = hw[2] | (hw[3] << 16); }
          else        { w2 = hw[0] | (hw[1] << 16); w3 = hw[2] | (hw[3] << 16); }
        }
        uint4 v; v.x = w0; v.y = w1; v.z = w2; v.w = w3;
        kp[(size_t)p * 64 + t] = v;
      }
      asm volatile("s_waitcnt vmcnt(0)" ::: "memory");   // data visible first
      if (t == 0) vflags[c] = 1;
    }
    return;   // producers exit (no barriers after this point)
  }

  // ------------- consumer (wave 0): verified R9 f64 DP -------------
  const char* kbase = (const char*)kp + t * 16;

  double EA[4] = {0.0, 0.0, 0.0, 0.0};
  double EB[4] = {0.0, 0.0, 0.0, 0.0};
  double dgc = 0.0;
  int Csum = 0;
  int cn = 0;       // last chunk whose loads were issued

#define WAITCH(c_) do {                                                       \
    while (vflags[c_] == 0) __builtin_amdgcn_s_sleep(2);                      \
    __builtin_amdgcn_sched_barrier(0);                                        \
  } while (0)

#define DPSTEP2(KAw, KBw, E2, E1, FIRSTF) do {                                \
    double K0_ = (double)__builtin_bit_cast(float, (KAw) << 16);              \
    double K1_ = (double)__builtin_bit_cast(float, (KAw) & 0xFFFF0000u);      \
    double K2_ = (double)__builtin_bit_cast(float, (KBw) << 16);              \
    double K3_ = (double)__builtin_bit_cast(float, (KBw) & 0xFFFF0000u);      \
    double up_ = shup1z_d(E1[3]);                                             \
    double dg_ = dgc;                                                         \
    if (FIRSTF) dg_ = (t == 0) ? 1.0 : dg_;                                   \
    double V0_ = K0_ * (dg_   + (up_   + E1[0]));                             \
    double V1_ = K1_ * (E2[0] + (E1[0] + E1[1]));                             \
    double V2_ = K2_ * (E2[1] + (E1[1] + E1[2]));                             \
    double V3_ = K3_ * (E2[2] + (E1[2] + E1[3]));                             \
    dgc = up_;                                                                \
    E2[0] = V0_; E2[1] = V1_; E2[2] = V2_; E2[3] = V3_;                       \
  } while (0)

#define RENORM(EN, EO) do {                                                   \
    double m4_ = fmax(fmax(EN[0], EN[1]), fmax(EN[2], EN[3]));                \
    float mh_ = __builtin_bit_cast(float, __double2hiint(m4_));               \
    mh_ = wave_max63(mh_);                                                    \
    int mb_ = __builtin_amdgcn_readlane(__builtin_bit_cast(int, mh_), 63);    \
    int s_ = (mb_ == 0) ? 0 : (1823 - ((mb_ >> 20) & 0x7FF));                 \
    EN[0] = ldexp(EN[0], s_); EN[1] = ldexp(EN[1], s_);                       \
    EN[2] = ldexp(EN[2], s_); EN[3] = ldexp(EN[3], s_);                       \
    EO[0] = ldexp(EO[0], s_); EO[1] = ldexp(EO[1], s_);                       \
    EO[2] = ldexp(EO[2], s_); EO[3] = ldexp(EO[3], s_);                       \
    dgc = ldexp(dgc, s_);                                                     \
    Csum += s_;                                                               \
  } while (0)

#define CHUNK16(CB, LB, FIRSTF) do {                                          \
    WAITCH(cn + 1);                                                           \
    LB[0] = *(const uint4*)(kbase);                                           \
    LB[1] = *(const uint4*)(kbase + 1024);                                    \
    LB[2] = *(const uint4*)(kbase + 2048);                                    \
    LB[3] = *(const uint4*)(kbase + 3072);                                    \
    LB[4] = *(const uint4*)(kbase + 4096);                                    \
    LB[5] = *(const uint4*)(kbase + 5120);                                    \
    LB[6] = *(const uint4*)(kbase + 6144);                                    \
    LB[7] = *(const uint4*)(kbase + 7168);                                    \
    kbase += 8192; cn += 1;                                                   \
    __builtin_amdgcn_sched_barrier(0);                                        \
    DPSTEP2(CB[0].x, CB[0].y, EA, EB, FIRSTF);                                \
    DPSTEP2(CB[0].z, CB[0].w, EB, EA, false);                                 \
    DPSTEP2(CB[1].x, CB[1].y, EA, EB, false);                                 \
    DPSTEP2(CB[1].z, CB[1].w, EB, EA, false);                                 \
    DPSTEP2(CB[2].x, CB[2].y, EA, EB, false);                                 \
    DPSTEP2(CB[2].z, CB[2].w, EB, EA, false);                                 \
    DPSTEP2(CB[3].x, CB[3].y, EA, EB, false);                                 \
    DPSTEP2(CB[3].z, CB[3].w, EB, EA, false);                                 \
    RENORM(EB, EA);                                                           \
    DPSTEP2(CB[4].x, CB[4].y, EA, EB, false);                                 \
    DPSTEP2(CB[4].z, CB[4].w, EB, EA, false);                                 \
    DPSTEP2(CB[5].x, CB[5].y, EA, EB, false);                                 \
    DPSTEP2(CB[5].z, CB[5].w, EB, EA, false);                                 \
    DPSTEP2(CB[6].x, CB[6].y, EA, EB, false);                                 \
    DPSTEP2(CB[6].z, CB[6].w, EB, EA, false);                                 \
    DPSTEP2(CB[7].x, CB[7].y, EA, EB, false);                                 \
    DPSTEP2(CB[7].z, CB[7].w, EB, EA, false);                                 \
    RENORM(EB, EA);                                                           \
  } while (0)

  uint4 KA[8], KB[8];
  WAITCH(0);
  KA[0] = *(const uint4*)(kbase);
  KA[1] = *(const uint4*)(kbase + 1024);
  KA[2] = *(const uint4*)(kbase + 2048);
  KA[3] = *(const uint4*)(kbase + 3072);
  KA[4] = *(const uint4*)(kbase + 4096);
  KA[5] = *(const uint4*)(kbase + 5120);
  KA[6] = *(const uint4*)(kbase + 6144);
  KA[7] = *(const uint4*)(kbase + 7168);
  kbase += 8192;

  CHUNK16(KA, KB, true);            // chunk 0 (steps 0..15), loads chunk 1
  #pragma unroll 1
  for (int c = 0; c < 15; ++c) {    // chunks 1..30 (steps 16..495)
    CHUNK16(KB, KA, false);
    CHUNK16(KA, KB, false);
  }
  // tail: steps 496..510 from KB (chunk 31), no loads
  DPSTEP2(KB[0].x, KB[0].y, EA, EB, false);
  DPSTEP2(KB[0].z, KB[0].w, EB, EA, false);
  DPSTEP2(KB[1].x, KB[1].y, EA, EB, false);
  DPSTEP2(KB[1].z, KB[1].w, EB, EA, false);
  DPSTEP2(KB[2].x, KB[2].y, EA, EB, false);
  DPSTEP2(KB[2].z, KB[2].w, EB, EA, false);
  DPSTEP2(KB[3].x, KB[3].y, EA, EB, false);
  DPSTEP2(KB[3].z, KB[3].w, EB, EA, false);
  RENORM(EB, EA);
  DPSTEP2(KB[4].x, KB[4].y, EA, EB, false);
  DPSTEP2(KB[4].z, KB[4].w, EB, EA, false);
  DPSTEP2(KB[5].x, KB[5].y, EA, EB, false);
  DPSTEP2(KB[5].z, KB[5].w, EB, EA, false);
  DPSTEP2(KB[6].x, KB[6].y, EA, EB, false);
  DPSTEP2(KB[6].z, KB[6].w, EB, EA, false);
  DPSTEP2(KB[7].x, KB[7].y, EA, EB, false);   // step 510 -> EA, result EA[3]

  if (t == 63) {
    int ex;
    double mant = frexp(EA[3], &ex);   // mant in [0.5, 1)
    float l2 = (float)ex + flog2((float)mant);
    out[b] = (float)(LN2 * ((double)Csum - (double)l2));
  }
}

// ---------------- fallback (R1 log-domain kernel), used if ws too small -----
__global__ __launch_bounds__(64) void softdtw_fallback(
    const float* __restrict__ x, const float* __restrict__ y,
    float* __restrict__ out)
{
  const int b = blockIdx.x;
  const int t = threadIdx.x;
  __shared__ float zbuf[4][64][9];
  const float* xb = x + (size_t)b * 256 * 8;
  const float* yb = y + (size_t)b * 256 * 8;
  float xe[4][9];
  float x2L[4];
  #pragma unroll
  for (int r = 0; r < 4; ++r) {
    const int row = 4 * t + r;
    float4 a = *(const float4*)(yb + row * 8);
    float4 c = *(const float4*)(yb + row * 8 + 4);
    float y2 = a.x*a.x + a.y*a.y + a.z*a.z + a.w*a.w
             + c.x*c.x + c.y*c.y + c.z*c.z + c.w*c.w;
    float* zr = &zbuf[r][t][0];
    zr[0] = -2.0f*L2E*a.x; zr[1] = -2.0f*L2E*a.y; zr[2] = -2.0f*L2E*a.z; zr[3] = -2.0f*L2E*a.w;
    zr[4] = -2.0f*L2E*c.x; zr[5] = -2.0f*L2E*c.y; zr[6] = -2.0f*L2E*c.z; zr[7] = -2.0f*L2E*c.w;
    zr[8] = L2E * y2;
    float4 xa = *(const float4*)(xb + row * 8);
    float4 xc = *(const float4*)(xb + row * 8 + 4);
    xe[r][0]=xa.x; xe[r][1]=xa.y; xe[r][2]=xa.z; xe[r][3]=xa.w;
    xe[r][4]=xc.x; xe[r][5]=xc.y; xe[r][6]=xc.z; xe[r][7]=xc.w; xe[r][8]=1.0f;
    x2L[r] = L2E*(xa.x*xa.x + xa.y*xa.y + xa.z*xa.z + xa.w*xa.w
                + xc.x*xc.x + xc.y*xc.y + xc.z*xc.z + xc.w*xc.w);
  }
  __syncthreads();
  float zA[9], zB[9], zC[9], zD[9];
  #pragma unroll
  for (int w = 0; w < 9; ++w) { zA[w]=0.f; zB[w]=0.f; zC[w]=0.f; zD[w]=0.f; }
  float RA[4] = {BIGL,BIGL,BIGL,BIGL};
  float RB[4] = {BIGL,BIGL,BIGL,BIGL};
  int u = -4 * t;
  auto ROW = [&](int r, float a, float bb, float c, const float (&zr)[9]) -> float {
    float acc = x2L[r];
    #pragma unroll
    for (int d = 0; d < 9; ++d) acc = fmaf(xe[r][d], zr[d], acc);
    float m = fminf(fminf(a, bb), c);
    float e = fexp2(m-a) + fexp2(m-bb) + fexp2(m-c);
    float val = acc + (m - flog2(e));
    return ((unsigned)(u - r) < 256u) ? val : BIGL;
  };
  auto STEP = [&](float (&zw)[9], const float (&zx)[9], const float (&zy)[9],
                  const float (&zz)[9], float (&Rm2)[4], float (&Rm1)[4],
                  int p, int k) {
    int uc = u < 0 ? 0 : (u > 255 ? 255 : u);
    const float* zp = &zbuf[p][uc >> 2][0];
    #pragma unroll
    for (int w = 0; w < 9; ++w) zw[w] = zp[w];
    float up_in = __shfl_up(Rm1[3], 1);
    float dg_in = __shfl_up(Rm2[3], 1);
    float bval = (k == 2) ? 0.0f : BIGL;
    if (t == 0) { up_in = BIGL; dg_in = bval; }
    float n0 = ROW(0, dg_in,  up_in,  Rm1[0], zw);
    float n1 = ROW(1, Rm2[0], Rm1[0], Rm1[1], zx);
    float n2 = ROW(2, Rm2[1], Rm1[1], Rm1[2], zy);
    float n3 = ROW(3, Rm2[2], Rm1[2], Rm1[3], zz);
    Rm2[0]=n0; Rm2[1]=n1; Rm2[2]=n2; Rm2[3]=n3;
    u += 1;
  };
  int k = 2;
  for (int mi = 0; mi < 127; ++mi) {
    STEP(zD, zA, zB, zC, RA, RB, 0, k);
    STEP(zC, zD, zA, zB, RB, RA, 1, k + 1);
    STEP(zB, zC, zD, zA, RA, RB, 2, k + 2);
    STEP(zA, zB, zC, zD, RB, RA, 3, k + 3);
    k += 4;
  }
  STEP(zD, zA, zB, zC, RA, RB, 0, k);
  STEP(zC, zD, zA, zB, RB, RA, 1, k + 1);
  STEP(zB, zC, zD, zA, RA, RB, 2, k + 2);
  if (t == 63) out[b] = RA[3] * LN2;
}

extern "C" void kernel_launch(void* const* d_in, const int* in_sizes, int n_in,
                              void* d_out, int out_size, void* d_ws, size_t ws_size,
                              hipStream_t stream) {
  const float* x = (const float*)d_in[0];
  const float* y = (const float*)d_in[1];
  float* out = (float*)d_out;
  const int B = in_sizes[0] / (256 * 8);
  const size_t need = (size_t)B * 262144;   // 256 diag-pairs x 64 lanes x 16B
  if (ws_size >= need) {
    uint4* Kp4 = (uint4*)d_ws;
    softdtw_fused<<<dim3(B), dim3(256), 0, stream>>>(x, y, Kp4, out);
  } else {
    softdtw_fallback<<<dim3(B), dim3(64), 0, stream>>>(x, y, out);
  }
}

// Round 13
// 87.719 us; speedup vs baseline: 1.0844x; 1.0844x over previous
//
#include <hip/hip_runtime.h>

#ifndef __has_builtin
#define __has_builtin(x) 0
#endif

#if __has_builtin(__builtin_amdgcn_logf)
__device__ __forceinline__ float flog2(float x) { return __builtin_amdgcn_logf(x); }
#else
__device__ __forceinline__ float flog2(float x) { return log2f(x); }
#endif
#if __has_builtin(__builtin_amdgcn_exp2f)
__device__ __forceinline__ float fexp2(float x) { return __builtin_amdgcn_exp2f(x); }
#else
__device__ __forceinline__ float fexp2(float x) { return exp2f(x); }
#endif

#define L2E 1.4426950408889634f   // log2(e)
#define LN2 0.6931471805599453
#define BIGL (1.0e10f * L2E)

template <int CTRL, int RM, int BM>
__device__ __forceinline__ float dpp_f(float v, float old) {
  int r = __builtin_amdgcn_update_dpp(__builtin_bit_cast(int, old),
                                      __builtin_bit_cast(int, v),
                                      CTRL, RM, BM, false);
  return __builtin_bit_cast(float, r);
}

// lane i <- lane i-1; lane 0 <- 0. fp64 via DPP on both halves.
__device__ __forceinline__ double shup1z_d(double v) {
  int lo = __double2loint(v), hi = __double2hiint(v);
  int lo2 = __builtin_amdgcn_update_dpp(0, lo, 0x138, 0xF, 0xF, false);
  int hi2 = __builtin_amdgcn_update_dpp(0, hi, 0x138, 0xF, 0xF, false);
  return __hiloint2double(hi2, lo2);
}

// wave max -> lane 63 (nonnegative floats)
__device__ __forceinline__ float wave_max63(float m) {
  m = fmaxf(m, dpp_f<0x111, 0xF, 0xF>(m, m));  // row_shr:1
  m = fmaxf(m, dpp_f<0x112, 0xF, 0xF>(m, m));  // row_shr:2
  m = fmaxf(m, dpp_f<0x114, 0xF, 0xF>(m, m));  // row_shr:4
  m = fmaxf(m, dpp_f<0x118, 0xF, 0xF>(m, m));  // row_shr:8
  m = fmaxf(m, dpp_f<0x142, 0xA, 0xF>(m, m));  // row_bcast15 -> rows 1,3
  m = fmaxf(m, dpp_f<0x143, 0xC, 0xF>(m, m));  // row_bcast31 -> rows 2,3
  return m;
}

// ---------------- prep: K = bf16(exp(-||x_i - y_j||^2)), PAIR-major layout --
// y staged in LDS ([8][257] padded: lane-stride-1 reads, conflict-free) to
// lift the L1 64B/cyc bound (R12 post-mortem: prep was L1-bound ~13us).
// Kp4[b*16384 + kk2*64 + tt] : 16B = lane tt's 4 cells for diag pair
// {2*kk2, 2*kk2+1}. Diag slot 511 = tileK row 63 of last block = zeros.
__global__ __launch_bounds__(256) void softdtw_prep(
    const float* __restrict__ x, const float* __restrict__ y,
    uint4* __restrict__ Kp4, int B)
{
  const int b  = blockIdx.x % B;            // XCD-aligned with dp block
  const int K0 = (blockIdx.x / B) << 6;
  const int i0 = threadIdx.x;               // 0..255

  __shared__ __align__(16) unsigned short tileK[64][256];   // 32 KB
  __shared__ float ytile[8][257];                            // 8.2 KB

  const float* xb = x + ((size_t)b * 256 + i0) * 8;
  float4 xa = *(const float4*)(xb);
  float4 xc = *(const float4*)(xb + 4);
  const float* yb = y + (size_t)b * 256 * 8;

  {
    float4 ya = *(const float4*)(yb + i0 * 8);
    float4 yc = *(const float4*)(yb + i0 * 8 + 4);
    ytile[0][i0] = ya.x; ytile[1][i0] = ya.y;
    ytile[2][i0] = ya.z; ytile[3][i0] = ya.w;
    ytile[4][i0] = yc.x; ytile[5][i0] = yc.y;
    ytile[6][i0] = yc.z; ytile[7][i0] = yc.w;
  }
  __syncthreads();

  for (int jj = 0; jj < 64; ++jj) {
    int j0 = K0 + jj - i0;
    bool valid = (unsigned)j0 < 256u;
    int jc = j0 < 0 ? 0 : (j0 > 255 ? 255 : j0);
    float d, D;
    d = xa.x - ytile[0][jc]; D = d * d;
    d = xa.y - ytile[1][jc]; D = fmaf(d, d, D);
    d = xa.z - ytile[2][jc]; D = fmaf(d, d, D);
    d = xa.w - ytile[3][jc]; D = fmaf(d, d, D);
    d = xc.x - ytile[4][jc]; D = fmaf(d, d, D);
    d = xc.y - ytile[5][jc]; D = fmaf(d, d, D);
    d = xc.z - ytile[6][jc]; D = fmaf(d, d, D);
    d = xc.w - ytile[7][jc]; D = fmaf(d, d, D);
    float K = valid ? fexp2(-L2E * D) : 0.0f;
    unsigned kb = __builtin_bit_cast(unsigned, K);
    unsigned rn = (kb + 0x7FFFu + ((kb >> 16) & 1u)) >> 16;   // RNE to bf16
    tileK[jj][i0] = (unsigned short)rn;
  }
  __syncthreads();

  const size_t obase4 = (size_t)b * 16384;
  #pragma unroll
  for (int w = 0; w < 8; ++w) {
    int p = threadIdx.x + (w << 8);
    int kkP = p >> 6;
    int tt = p & 63;
    uint2 lo = *(const uint2*)&tileK[kkP * 2][tt * 4];
    uint2 hi = *(const uint2*)&tileK[kkP * 2 + 1][tt * 4];
    uint4 v; v.x = lo.x; v.y = lo.y; v.z = hi.x; v.w = hi.y;
    Kp4[obase4 + (size_t)((K0 >> 1) + kkP) * 64 + tt] = v;
  }
}

// ---------------- DP: f64 common-scale, TWO batches interleaved per wave ----
// Per batch: numerics byte-identical to the verified R9 kernel (renorm every
// 8 steps, target 2^850). The two independent step chains (A,B) alternate so
// each fills the other's f64-latency and renorm-readlane bubbles (occupancy
// is 1 wave/SIMD; ILP is the only latency hiding available).
__global__ __launch_bounds__(64) void softdtw_dp2(
    const uint4* __restrict__ Kp4, float* __restrict__ out)
{
  const int blk = blockIdx.x;
  const int t = threadIdx.x;

  const char* kbA = (const char*)(Kp4 + (size_t)(2 * blk)     * 16384) + t * 16;
  const char* kbB = (const char*)(Kp4 + (size_t)(2 * blk + 1) * 16384) + t * 16;

  double AEA[4] = {0.0, 0.0, 0.0, 0.0};
  double AEB[4] = {0.0, 0.0, 0.0, 0.0};
  double BEA[4] = {0.0, 0.0, 0.0, 0.0};
  double BEB[4] = {0.0, 0.0, 0.0, 0.0};
  double dgcA = 0.0, dgcB = 0.0;
  int CsA = 0, CsB = 0;

#define DPSTEP2(KAw, KBw, E2, E1, DGC, FIRSTF) do {                           \
    double K0_ = (double)__builtin_bit_cast(float, (KAw) << 16);              \
    double K1_ = (double)__builtin_bit_cast(float, (KAw) & 0xFFFF0000u);      \
    double K2_ = (double)__builtin_bit_cast(float, (KBw) << 16);              \
    double K3_ = (double)__builtin_bit_cast(float, (KBw) & 0xFFFF0000u);      \
    double up_ = shup1z_d(E1[3]);                                             \
    double dg_ = DGC;                                                         \
    if (FIRSTF) dg_ = (t == 0) ? 1.0 : dg_;                                   \
    double V0_ = K0_ * (dg_   + (up_   + E1[0]));                             \
    double V1_ = K1_ * (E2[0] + (E1[0] + E1[1]));                             \
    double V2_ = K2_ * (E2[1] + (E1[1] + E1[2]));                             \
    double V3_ = K3_ * (E2[2] + (E1[2] + E1[3]));                             \
    DGC = up_;                                                                \
    E2[0] = V0_; E2[1] = V1_; E2[2] = V2_; E2[3] = V3_;                       \
  } while (0)

#define RENORM(EN, EO, DGC, CS) do {                                          \
    double m4_ = fmax(fmax(EN[0], EN[1]), fmax(EN[2], EN[3]));                \
    float mh_ = __builtin_bit_cast(float, __double2hiint(m4_));               \
    mh_ = wave_max63(mh_);                                                    \
    int mb_ = __builtin_amdgcn_readlane(__builtin_bit_cast(int, mh_), 63);    \
    int s_ = (mb_ == 0) ? 0 : (1823 - ((mb_ >> 20) & 0x7FF));                 \
    EN[0] = ldexp(EN[0], s_); EN[1] = ldexp(EN[1], s_);                       \
    EN[2] = ldexp(EN[2], s_); EN[3] = ldexp(EN[3], s_);                       \
    EO[0] = ldexp(EO[0], s_); EO[1] = ldexp(EO[1], s_);                       \
    EO[2] = ldexp(EO[2], s_); EO[3] = ldexp(EO[3], s_);                       \
    DGC = ldexp(DGC, s_);                                                     \
    CS += s_;                                                                 \
  } while (0)

  // one 8-step chunk (4 diag-pairs) for BOTH batches, A/B interleaved.
  // Loads chunk c+1 at top (sched_barrier-pinned), consumes buffer CA/CBb.
#define CHUNK8(CA, LA, CBb, LBb, FIRSTF) do {                                 \
    LA[0] = *(const uint4*)(kbA);                                             \
    LA[1] = *(const uint4*)(kbA + 1024);                                      \
    LA[2] = *(const uint4*)(kbA + 2048);                                      \
    LA[3] = *(const uint4*)(kbA + 3072);                                      \
    LBb[0] = *(const uint4*)(kbB);                                            \
    LBb[1] = *(const uint4*)(kbB + 1024);                                     \
    LBb[2] = *(const uint4*)(kbB + 2048);                                     \
    LBb[3] = *(const uint4*)(kbB + 3072);                                     \
    kbA += 4096; kbB += 4096;                                                 \
    __builtin_amdgcn_sched_barrier(0);                                        \
    DPSTEP2(CA[0].x,  CA[0].y,  AEA, AEB, dgcA, FIRSTF);                      \
    DPSTEP2(CBb[0].x, CBb[0].y, BEA, BEB, dgcB, FIRSTF);                      \
    DPSTEP2(CA[0].z,  CA[0].w,  AEB, AEA, dgcA, false);                       \
    DPSTEP2(CBb[0].z, CBb[0].w, BEB, BEA, dgcB, false);                       \
    DPSTEP2(CA[1].x,  CA[1].y,  AEA, AEB, dgcA, false);                       \
    DPSTEP2(CBb[1].x, CBb[1].y, BEA, BEB, dgcB, false);                       \
    DPSTEP2(CA[1].z,  CA[1].w,  AEB, AEA, dgcA, false);                       \
    DPSTEP2(CBb[1].z, CBb[1].w, BEB, BEA, dgcB, false);                       \
    DPSTEP2(CA[2].x,  CA[2].y,  AEA, AEB, dgcA, false);                       \
    DPSTEP2(CBb[2].x, CBb[2].y, BEA, BEB, dgcB, false);                       \
    DPSTEP2(CA[2].z,  CA[2].w,  AEB, AEA, dgcA, false);                       \
    DPSTEP2(CBb[2].z, CBb[2].w, BEB, BEA, dgcB, false);                       \
    DPSTEP2(CA[3].x,  CA[3].y,  AEA, AEB, dgcA, false);                       \
    DPSTEP2(CBb[3].x, CBb[3].y, BEA, BEB, dgcB, false);                       \
    DPSTEP2(CA[3].z,  CA[3].w,  AEB, AEA, dgcA, false);                       \
    DPSTEP2(CBb[3].z, CBb[3].w, BEB, BEA, dgcB, false);                       \
    RENORM(AEB, AEA, dgcA, CsA);                                              \
    RENORM(BEB, BEA, dgcB, CsB);                                              \
  } while (0)

  uint4 A0[4], A1[4], B0[4], B1[4];
  A0[0] = *(const uint4*)(kbA);
  A0[1] = *(const uint4*)(kbA + 1024);
  A0[2] = *(const uint4*)(kbA + 2048);
  A0[3] = *(const uint4*)(kbA + 3072);
  B0[0] = *(const uint4*)(kbB);
  B0[1] = *(const uint4*)(kbB + 1024);
  B0[2] = *(const uint4*)(kbB + 2048);
  B0[3] = *(const uint4*)(kbB + 3072);
  kbA += 4096; kbB += 4096;

  CHUNK8(A0, A1, B0, B1, true);        // chunk 0 (steps 0..7), loads chunk 1
  #pragma unroll 1
  for (int c = 0; c < 31; ++c) {       // chunks 1..62 (steps 8..503)
    CHUNK8(A1, A0, B1, B0, false);
    CHUNK8(A0, A1, B0, B1, false);
  }
  // chunk 62 computed above loaded chunk 63 -> buffers A1/B1.
  // tail: steps 504..510 (7 steps) from A1/B1, no loads.
  DPSTEP2(A1[0].x, A1[0].y, AEA, AEB, dgcA, false);
  DPSTEP2(B1[0].x, B1[0].y, BEA, BEB, dgcB, false);
  DPSTEP2(A1[0].z, A1[0].w, AEB, AEA, dgcA, false);
  DPSTEP2(B1[0].z, B1[0].w, BEB, BEA, dgcB, false);
  DPSTEP2(A1[1].x, A1[1].y, AEA, AEB, dgcA, false);
  DPSTEP2(B1[1].x, B1[1].y, BEA, BEB, dgcB, false);
  DPSTEP2(A1[1].z, A1[1].w, AEB, AEA, dgcA, false);
  DPSTEP2(B1[1].z, B1[1].w, BEB, BEA, dgcB, false);
  DPSTEP2(A1[2].x, A1[2].y, AEA, AEB, dgcA, false);
  DPSTEP2(B1[2].x, B1[2].y, BEA, BEB, dgcB, false);
  DPSTEP2(A1[2].z, A1[2].w, AEB, AEA, dgcA, false);
  DPSTEP2(B1[2].z, B1[2].w, BEB, BEA, dgcB, false);
  DPSTEP2(A1[3].x, A1[3].y, AEA, AEB, dgcA, false);   // step 510 -> AEA/BEA
  DPSTEP2(B1[3].x, B1[3].y, BEA, BEB, dgcB, false);

  if (t == 63) {
    int ex;
    double mant = frexp(AEA[3], &ex);
    float l2 = (float)ex + flog2((float)mant);
    out[2 * blk] = (float)(LN2 * ((double)CsA - (double)l2));
    mant = frexp(BEA[3], &ex);
    l2 = (float)ex + flog2((float)mant);
    out[2 * blk + 1] = (float)(LN2 * ((double)CsB - (double)l2));
  }
}

// ---------------- fallback (R1 log-domain kernel), used if ws too small -----
__global__ __launch_bounds__(64) void softdtw_fallback(
    const float* __restrict__ x, const float* __restrict__ y,
    float* __restrict__ out)
{
  const int b = blockIdx.x;
  const int t = threadIdx.x;
  __shared__ float zbuf[4][64][9];
  const float* xb = x + (size_t)b * 256 * 8;
  const float* yb = y + (size_t)b * 256 * 8;
  float xe[4][9];
  float x2L[4];
  #pragma unroll
  for (int r = 0; r < 4; ++r) {
    const int row = 4 * t + r;
    float4 a = *(const float4*)(yb + row * 8);
    float4 c = *(const float4*)(yb + row * 8 + 4);
    float y2 = a.x*a.x + a.y*a.y + a.z*a.z + a.w*a.w
             + c.x*c.x + c.y*c.y + c.z*c.z + c.w*c.w;
    float* zr = &zbuf[r][t][0];
    zr[0] = -2.0f*L2E*a.x; zr[1] = -2.0f*L2E*a.y; zr[2] = -2.0f*L2E*a.z; zr[3] = -2.0f*L2E*a.w;
    zr[4] = -2.0f*L2E*c.x; zr[5] = -2.0f*L2E*c.y; zr[6] = -2.0f*L2E*c.z; zr[7] = -2.0f*L2E*c.w;
    zr[8] = L2E * y2;
    float4 xa = *(const float4*)(xb + row * 8);
    float4 xc = *(const float4*)(xb + row * 8 + 4);
    xe[r][0]=xa.x; xe[r][1]=xa.y; xe[r][2]=xa.z; xe[r][3]=xa.w;
    xe[r][4]=xc.x; xe[r][5]=xc.y; xe[r][6]=xc.z; xe[r][7]=xc.w; xe[r][8]=1.0f;
    x2L[r] = L2E*(xa.x*xa.x + xa.y*xa.y + xa.z*xa.z + xa.w*xa.w
                + xc.x*xc.x + xc.y*xc.y + xc.z*xc.z + xc.w*xc.w);
  }
  __syncthreads();
  float zA[9], zB[9], zC[9], zD[9];
  #pragma unroll
  for (int w = 0; w < 9; ++w) { zA[w]=0.f; zB[w]=0.f; zC[w]=0.f; zD[w]=0.f; }
  float RA[4] = {BIGL,BIGL,BIGL,BIGL};
  float RB[4] = {BIGL,BIGL,BIGL,BIGL};
  int u = -4 * t;
  auto ROW = [&](int r, float a, float bb, float c, const float (&zr)[9]) -> float {
    float acc = x2L[r];
    #pragma unroll
    for (int d = 0; d < 9; ++d) acc = fmaf(xe[r][d], zr[d], acc);
    float m = fminf(fminf(a, bb), c);
    float e = fexp2(m-a) + fexp2(m-bb) + fexp2(m-c);
    float val = acc + (m - flog2(e));
    return ((unsigned)(u - r) < 256u) ? val : BIGL;
  };
  auto STEP = [&](float (&zw)[9], const float (&zx)[9], const float (&zy)[9],
                  const float (&zz)[9], float (&Rm2)[4], float (&Rm1)[4],
                  int p, int k) {
    int uc = u < 0 ? 0 : (u > 255 ? 255 : u);
    const float* zp = &zbuf[p][uc >> 2][0];
    #pragma unroll
    for (int w = 0; w < 9; ++w) zw[w] = zp[w];
    float up_in = __shfl_up(Rm1[3], 1);
    float dg_in = __shfl_up(Rm2[3], 1);
    float bval = (k == 2) ? 0.0f : BIGL;
    if (t == 0) { up_in = BIGL; dg_in = bval; }
    float n0 = ROW(0, dg_in,  up_in,  Rm1[0], zw);
    float n1 = ROW(1, Rm2[0], Rm1[0], Rm1[1], zx);
    float n2 = ROW(2, Rm2[1], Rm1[1], Rm1[2], zy);
    float n3 = ROW(3, Rm2[2], Rm1[2], Rm1[3], zz);
    Rm2[0]=n0; Rm2[1]=n1; Rm2[2]=n2; Rm2[3]=n3;
    u += 1;
  };
  int k = 2;
  for (int mi = 0; mi < 127; ++mi) {
    STEP(zD, zA, zB, zC, RA, RB, 0, k);
    STEP(zC, zD, zA, zB, RB, RA, 1, k + 1);
    STEP(zB, zC, zD, zA, RA, RB, 2, k + 2);
    STEP(zA, zB, zC, zD, RB, RA, 3, k + 3);
    k += 4;
  }
  STEP(zD, zA, zB, zC, RA, RB, 0, k);
  STEP(zC, zD, zA, zB, RB, RA, 1, k + 1);
  STEP(zB, zC, zD, zA, RA, RB, 2, k + 2);
  if (t == 63) out[b] = RA[3] * LN2;
}

extern "C" void kernel_launch(void* const* d_in, const int* in_sizes, int n_in,
                              void* d_out, int out_size, void* d_ws, size_t ws_size,
                              hipStream_t stream) {
  const float* x = (const float*)d_in[0];
  const float* y = (const float*)d_in[1];
  float* out = (float*)d_out;
  const int B = in_sizes[0] / (256 * 8);
  const size_t need = (size_t)B * 262144;   // 256 diag-pairs x 64 lanes x 16B
  if (ws_size >= need && (B % 2) == 0) {
    uint4* Kp4 = (uint4*)d_ws;
    softdtw_prep<<<dim3(B * 8), dim3(256), 0, stream>>>(x, y, Kp4, B);
    softdtw_dp2<<<dim3(B / 2), dim3(64), 0, stream>>>(Kp4, out);
  } else {
    softdtw_fallback<<<dim3(B), dim3(64), 0, stream>>>(x, y, out);
  }
}

// Round 14
// 65.199 us; speedup vs baseline: 1.4590x; 1.3454x over previous
//
#include <hip/hip_runtime.h>

#ifndef __has_builtin
#define __has_builtin(x) 0
#endif

#if __has_builtin(__builtin_amdgcn_logf)
__device__ __forceinline__ float flog2(float x) { return __builtin_amdgcn_logf(x); }
#else
__device__ __forceinline__ float flog2(float x) { return log2f(x); }
#endif
#if __has_builtin(__builtin_amdgcn_exp2f)
__device__ __forceinline__ float fexp2(float x) { return __builtin_amdgcn_exp2f(x); }
#else
__device__ __forceinline__ float fexp2(float x) { return exp2f(x); }
#endif

#define L2E 1.4426950408889634f   // log2(e)
#define LN2 0.6931471805599453
#define BIGL (1.0e10f * L2E)

template <int CTRL, int RM, int BM>
__device__ __forceinline__ float dpp_f(float v, float old) {
  int r = __builtin_amdgcn_update_dpp(__builtin_bit_cast(int, old),
                                      __builtin_bit_cast(int, v),
                                      CTRL, RM, BM, false);
  return __builtin_bit_cast(float, r);
}

// lane i <- lane i-1; lane 0 <- 0. fp64 via DPP on both halves (wave_shr:1).
__device__ __forceinline__ double shup1z_d(double v) {
  int lo = __double2loint(v), hi = __double2hiint(v);
  int lo2 = __builtin_amdgcn_update_dpp(0, lo, 0x138, 0xF, 0xF, false);
  int hi2 = __builtin_amdgcn_update_dpp(0, hi, 0x138, 0xF, 0xF, false);
  return __hiloint2double(hi2, lo2);
}

// rotate: lane i <- lane (i-1)&63, so lane 0 <- lane 63 (wave_ror:1).
__device__ __forceinline__ double ror1_d(double v) {
  int lo = __double2loint(v), hi = __double2hiint(v);
  int lo2 = __builtin_amdgcn_update_dpp(0, lo, 0x13C, 0xF, 0xF, false);
  int hi2 = __builtin_amdgcn_update_dpp(0, hi, 0x13C, 0xF, 0xF, false);
  return __hiloint2double(hi2, lo2);
}

// wave max -> lane 63 (nonnegative floats)
__device__ __forceinline__ float wave_max63(float m) {
  m = fmaxf(m, dpp_f<0x111, 0xF, 0xF>(m, m));  // row_shr:1
  m = fmaxf(m, dpp_f<0x112, 0xF, 0xF>(m, m));  // row_shr:2
  m = fmaxf(m, dpp_f<0x114, 0xF, 0xF>(m, m));  // row_shr:4
  m = fmaxf(m, dpp_f<0x118, 0xF, 0xF>(m, m));  // row_shr:8
  m = fmaxf(m, dpp_f<0x142, 0xA, 0xF>(m, m));  // row_bcast15 -> rows 1,3
  m = fmaxf(m, dpp_f<0x143, 0xC, 0xF>(m, m));  // row_bcast31 -> rows 2,3
  return m;
}

// ---------------- prep: K = bf16(exp(-||x_i - y_j||^2)), 2-CHAIN layout -----
// Chain c (0: rows 0..127, 1: rows 128..255), lane t owns rows 128c+2t,+1.
// Kp4[b*16384 + c*8192 + q*64 + t]: uint4 = 4 steps (diags 4q..4q+3), each
// uint = bf16(row 128c+2t) | bf16(row 128c+2t+1)<<16. Diag 511 slot = zeros.
__global__ __launch_bounds__(256) void softdtw_prep(
    const float* __restrict__ x, const float* __restrict__ y,
    uint4* __restrict__ Kp4, int B)
{
  const int b  = blockIdx.x % B;            // XCD-aligned with dp block b
  const int K0 = (blockIdx.x / B) << 6;
  const int i0 = threadIdx.x;               // 0..255

  __shared__ __align__(16) unsigned short tileK[64][256];   // [kkL][row]

  const float* xb = x + ((size_t)b * 256 + i0) * 8;
  float4 xa = *(const float4*)(xb);
  float4 xc = *(const float4*)(xb + 4);
  const float* yb = y + (size_t)b * 256 * 8;

  for (int jj = 0; jj < 64; ++jj) {
    int j0 = K0 + jj - i0;
    bool valid = (unsigned)j0 < 256u;
    int jc = j0 < 0 ? 0 : (j0 > 255 ? 255 : j0);
    const float4* yp = (const float4*)(yb + jc * 8);
    float4 ya = yp[0], yc = yp[1];
    float d, D;
    d = xa.x - ya.x; D = d * d;
    d = xa.y - ya.y; D = fmaf(d, d, D);
    d = xa.z - ya.z; D = fmaf(d, d, D);
    d = xa.w - ya.w; D = fmaf(d, d, D);
    d = xc.x - yc.x; D = fmaf(d, d, D);
    d = xc.y - yc.y; D = fmaf(d, d, D);
    d = xc.z - yc.z; D = fmaf(d, d, D);
    d = xc.w - yc.w; D = fmaf(d, d, D);
    float K = valid ? fexp2(-L2E * D) : 0.0f;
    unsigned kb = __builtin_bit_cast(unsigned, K);
    unsigned rn = (kb + 0x7FFFu + ((kb >> 16) & 1u)) >> 16;   // RNE to bf16
    tileK[jj][i0] = (unsigned short)rn;
  }
  __syncthreads();

  const size_t obase4 = (size_t)b * 16384;
  #pragma unroll
  for (int w = 0; w < 8; ++w) {
    int p = threadIdx.x + (w << 8);        // 0..2047
    int c  = p >> 10;                      // chain
    int qL = (p >> 6) & 15;                // local quad
    int tt = p & 63;
    int kkL = qL * 4;
    uint4 v;
    v.x = *(const unsigned*)&tileK[kkL + 0][128 * c + 2 * tt];
    v.y = *(const unsigned*)&tileK[kkL + 1][128 * c + 2 * tt];
    v.z = *(const unsigned*)&tileK[kkL + 2][128 * c + 2 * tt];
    v.w = *(const unsigned*)&tileK[kkL + 3][128 * c + 2 * tt];
    Kp4[obase4 + (size_t)c * 8192 + (size_t)((K0 >> 2) + qL) * 64 + tt] = v;
  }
}

// ---------------- DP: f64 common-scale, 2 row-chains per wave ---------------
// Chain A: rows 0..127 (diag s at step s); chain B: rows 128..255 (diag s-4).
// Boundary row127->row128 crosses lanes 63->0 via wave_ror:1 into an 8-slot
// register FIFO (produce slot s&7, consume (s+3)&7 = (s-5)&7). One common
// scale (renorm every 8 steps, target 2^850, exact 2^s scaling -> mantissa
// path identical to the verified R9 kernel). Borders come from K's zeros.
__global__ __launch_bounds__(64) void softdtw_dp(
    const uint4* __restrict__ Kp4, float* __restrict__ out)
{
  const int b = blockIdx.x;
  const int t = threadIdx.x;

  const char* pA = (const char*)(Kp4 + (size_t)b * 16384) + t * 16;
  const char* pB = pA + 131072;   // chain-B array (8192 uint4)

  double EA_A[2] = {0.0, 0.0}, EB_A[2] = {0.0, 0.0};
  double EA_B[2] = {0.0, 0.0}, EB_B[2] = {0.0, 0.0};
  double fifo[8] = {0.0, 0.0, 0.0, 0.0, 0.0, 0.0, 0.0, 0.0};
  double dgcA = 0.0, dgcB = 0.0;
  int Csum = 0;

#define STEPAB(sr, wA, wB, NA, PA, NB, PB, FIRSTF) do {                       \
    double KA0_ = (double)__builtin_bit_cast(float, (unsigned)(wA) << 16);    \
    double KA1_ = (double)__builtin_bit_cast(float, (unsigned)(wA) & 0xFFFF0000u); \
    double KB0_ = (double)__builtin_bit_cast(float, (unsigned)(wB) << 16);    \
    double KB1_ = (double)__builtin_bit_cast(float, (unsigned)(wB) & 0xFFFF0000u); \
    double upA_ = shup1z_d(PA[1]);                                            \
    double dgA_ = dgcA;                                                       \
    if (FIRSTF) dgA_ = (t == 0) ? 1.0 : dgA_;                                 \
    double nA0_ = KA0_ * (dgA_ + (upA_ + PA[0]));                             \
    double nA1_ = KA1_ * (NA[0] + (PA[0] + PA[1]));                           \
    dgcA = upA_; NA[0] = nA0_; NA[1] = nA1_;                                  \
    fifo[(sr) & 7] = ror1_d(nA1_);                                            \
    double upBr_ = shup1z_d(PB[1]);                                           \
    double upB_ = (t == 0) ? fifo[((sr) + 3) & 7] : upBr_;                    \
    double nB0_ = KB0_ * (dgcB + (upB_ + PB[0]));                             \
    double nB1_ = KB1_ * (NB[0] + (PB[0] + PB[1]));                           \
    dgcB = upB_; NB[0] = nB0_; NB[1] = nB1_;                                  \
  } while (0)

#define RENORM2() do {                                                        \
    double m4_ = fmax(fmax(EB_A[0], EB_A[1]), fmax(EB_B[0], EB_B[1]));        \
    float mh_ = __builtin_bit_cast(float, __double2hiint(m4_));               \
    mh_ = wave_max63(mh_);                                                    \
    int mb_ = __builtin_amdgcn_readlane(__builtin_bit_cast(int, mh_), 63);    \
    int s_ = (mb_ == 0) ? 0 : (1823 - ((mb_ >> 20) & 0x7FF));                 \
    EB_A[0] = ldexp(EB_A[0], s_); EB_A[1] = ldexp(EB_A[1], s_);               \
    EA_A[0] = ldexp(EA_A[0], s_); EA_A[1] = ldexp(EA_A[1], s_);               \
    EB_B[0] = ldexp(EB_B[0], s_); EB_B[1] = ldexp(EB_B[1], s_);               \
    EA_B[0] = ldexp(EA_B[0], s_); EA_B[1] = ldexp(EA_B[1], s_);               \
    dgcA = ldexp(dgcA, s_); dgcB = ldexp(dgcB, s_);                           \
    fifo[0] = ldexp(fifo[0], s_); fifo[1] = ldexp(fifo[1], s_);               \
    fifo[2] = ldexp(fifo[2], s_); fifo[3] = ldexp(fifo[3], s_);               \
    fifo[4] = ldexp(fifo[4], s_); fifo[5] = ldexp(fifo[5], s_);               \
    fifo[6] = ldexp(fifo[6], s_); fifo[7] = ldexp(fifo[7], s_);               \
    Csum += s_;                                                               \
  } while (0)

  // 8 steps: A consumes quads {2m,2m+1} (args A0_,A1_), B consumes {2m-1,2m}
  // (args B0_,B1_); PF loads next body's 4 quads into L*.
#define BODY8(A0_, A1_, B0_, B1_, LA0_, LA1_, LB0_, LB1_, FIRSTF, PF) do {    \
    if (PF) {                                                                 \
      LA0_ = *(const uint4*)(pA);                                             \
      LA1_ = *(const uint4*)(pA + 1024);                                      \
      LB0_ = *(const uint4*)(pB);                                             \
      LB1_ = *(const uint4*)(pB + 1024);                                      \
      pA += 2048; pB += 2048;                                                 \
    }                                                                         \
    __builtin_amdgcn_sched_barrier(0);                                        \
    STEPAB(0, (A0_).x, (B0_).x, EA_A, EB_A, EA_B, EB_B, FIRSTF);              \
    STEPAB(1, (A0_).y, (B0_).y, EB_A, EA_A, EB_B, EA_B, false);               \
    STEPAB(2, (A0_).z, (B0_).z, EA_A, EB_A, EA_B, EB_B, false);               \
    STEPAB(3, (A0_).w, (B0_).w, EB_A, EA_A, EB_B, EA_B, false);               \
    STEPAB(4, (A1_).x, (B1_).x, EA_A, EB_A, EA_B, EB_B, false);               \
    STEPAB(5, (A1_).y, (B1_).y, EB_A, EA_A, EB_B, EA_B, false);               \
    STEPAB(6, (A1_).z, (B1_).z, EA_A, EB_A, EA_B, EB_B, false);               \
    STEPAB(7, (A1_).w, (B1_).w, EB_A, EA_A, EB_B, EA_B, false);               \
    RENORM2();                                                                \
  } while (0)

  // B-only tail step (chain A finished); same B math as STEPAB.
#define STEPBONLY(sr, wB, NB, PB) do {                                        \
    double KB0_ = (double)__builtin_bit_cast(float, (unsigned)(wB) << 16);    \
    double KB1_ = (double)__builtin_bit_cast(float, (unsigned)(wB) & 0xFFFF0000u); \
    double upBr_ = shup1z_d(PB[1]);                                           \
    double upB_ = (t == 0) ? fifo[((sr) + 3) & 7] : upBr_;                    \
    double nB0_ = KB0_ * (dgcB + (upB_ + PB[0]));                             \
    double nB1_ = KB1_ * (NB[0] + (PB[0] + PB[1]));                           \
    dgcB = upB_; NB[0] = nB0_; NB[1] = nB1_;                                  \
  } while (0)

  uint4 AU0, AU1, BU0, BU1, AV0, AV1, BV0, BV1;
  // prologue: A quads {0,1}; B quad -1 = zeros, quad 0.
  AU0 = *(const uint4*)(pA);
  AU1 = *(const uint4*)(pA + 1024);
  pA += 2048;
  BU0.x = 0u; BU0.y = 0u; BU0.z = 0u; BU0.w = 0u;
  BU1 = *(const uint4*)(pB);
  pB += 1024;

  BODY8(AU0, AU1, BU0, BU1, AV0, AV1, BV0, BV1, true, true);   // body 0
  #pragma unroll 1
  for (int i = 0; i < 31; ++i) {                                // bodies 1..62
    BODY8(AV0, AV1, BV0, BV1, AU0, AU1, BU0, BU1, false, true);
    BODY8(AU0, AU1, BU0, BU1, AV0, AV1, BV0, BV1, false, true);
  }
  uint4 BT = *(const uint4*)(pB);                               // B quad 127
  BODY8(AV0, AV1, BV0, BV1, AU0, AU1, BU0, BU1, false, false);  // body 63

  // tail: steps 512..514 = B diags 508..510 (B quad 127 comps x,y,z)
  STEPBONLY(0, BT.x, EA_B, EB_B);   // step 512
  STEPBONLY(1, BT.y, EB_B, EA_B);   // step 513
  STEPBONLY(2, BT.z, EA_B, EB_B);   // step 514 -> diag 510, result EA_B[1]

  if (t == 63) {
    int ex;
    double mant = frexp(EA_B[1], &ex);   // mant in [0.5, 1)
    float l2 = (float)ex + flog2((float)mant);
    out[b] = (float)(LN2 * ((double)Csum - (double)l2));
  }
}

// ---------------- fallback (R1 log-domain kernel), used if ws too small -----
__global__ __launch_bounds__(64) void softdtw_fallback(
    const float* __restrict__ x, const float* __restrict__ y,
    float* __restrict__ out)
{
  const int b = blockIdx.x;
  const int t = threadIdx.x;
  __shared__ float zbuf[4][64][9];
  const float* xb = x + (size_t)b * 256 * 8;
  const float* yb = y + (size_t)b * 256 * 8;
  float xe[4][9];
  float x2L[4];
  #pragma unroll
  for (int r = 0; r < 4; ++r) {
    const int row = 4 * t + r;
    float4 a = *(const float4*)(yb + row * 8);
    float4 c = *(const float4*)(yb + row * 8 + 4);
    float y2 = a.x*a.x + a.y*a.y + a.z*a.z + a.w*a.w
             + c.x*c.x + c.y*c.y + c.z*c.z + c.w*c.w;
    float* zr = &zbuf[r][t][0];
    zr[0] = -2.0f*L2E*a.x; zr[1] = -2.0f*L2E*a.y; zr[2] = -2.0f*L2E*a.z; zr[3] = -2.0f*L2E*a.w;
    zr[4] = -2.0f*L2E*c.x; zr[5] = -2.0f*L2E*c.y; zr[6] = -2.0f*L2E*c.z; zr[7] = -2.0f*L2E*c.w;
    zr[8] = L2E * y2;
    float4 xa = *(const float4*)(xb + row * 8);
    float4 xc = *(const float4*)(xb + row * 8 + 4);
    xe[r][0]=xa.x; xe[r][1]=xa.y; xe[r][2]=xa.z; xe[r][3]=xa.w;
    xe[r][4]=xc.x; xe[r][5]=xc.y; xe[r][6]=xc.z; xe[r][7]=xc.w; xe[r][8]=1.0f;
    x2L[r] = L2E*(xa.x*xa.x + xa.y*xa.y + xa.z*xa.z + xa.w*xa.w
                + xc.x*xc.x + xc.y*xc.y + xc.z*xc.z + xc.w*xc.w);
  }
  __syncthreads();
  float zA[9], zB[9], zC[9], zD[9];
  #pragma unroll
  for (int w = 0; w < 9; ++w) { zA[w]=0.f; zB[w]=0.f; zC[w]=0.f; zD[w]=0.f; }
  float RA[4] = {BIGL,BIGL,BIGL,BIGL};
  float RB[4] = {BIGL,BIGL,BIGL,BIGL};
  int u = -4 * t;
  auto ROW = [&](int r, float a, float bb, float c, const float (&zr)[9]) -> float {
    float acc = x2L[r];
    #pragma unroll
    for (int d = 0; d < 9; ++d) acc = fmaf(xe[r][d], zr[d], acc);
    float m = fminf(fminf(a, bb), c);
    float e = fexp2(m-a) + fexp2(m-bb) + fexp2(m-c);
    float val = acc + (m - flog2(e));
    return ((unsigned)(u - r) < 256u) ? val : BIGL;
  };
  auto STEP = [&](float (&zw)[9], const float (&zx)[9], const float (&zy)[9],
                  const float (&zz)[9], float (&Rm2)[4], float (&Rm1)[4],
                  int p, int k) {
    int uc = u < 0 ? 0 : (u > 255 ? 255 : u);
    const float* zp = &zbuf[p][uc >> 2][0];
    #pragma unroll
    for (int w = 0; w < 9; ++w) zw[w] = zp[w];
    float up_in = __shfl_up(Rm1[3], 1);
    float dg_in = __shfl_up(Rm2[3], 1);
    float bval = (k == 2) ? 0.0f : BIGL;
    if (t == 0) { up_in = BIGL; dg_in = bval; }
    float n0 = ROW(0, dg_in,  up_in,  Rm1[0], zw);
    float n1 = ROW(1, Rm2[0], Rm1[0], Rm1[1], zx);
    float n2 = ROW(2, Rm2[1], Rm1[1], Rm1[2], zy);
    float n3 = ROW(3, Rm2[2], Rm1[2], Rm1[3], zz);
    Rm2[0]=n0; Rm2[1]=n1; Rm2[2]=n2; Rm2[3]=n3;
    u += 1;
  };
  int k = 2;
  for (int mi = 0; mi < 127; ++mi) {
    STEP(zD, zA, zB, zC, RA, RB, 0, k);
    STEP(zC, zD, zA, zB, RB, RA, 1, k + 1);
    STEP(zB, zC, zD, zA, RA, RB, 2, k + 2);
    STEP(zA, zB, zC, zD, RB, RA, 3, k + 3);
    k += 4;
  }
  STEP(zD, zA, zB, zC, RA, RB, 0, k);
  STEP(zC, zD, zA, zB, RB, RA, 1, k + 1);
  STEP(zB, zC, zD, zA, RA, RB, 2, k + 2);
  if (t == 63) out[b] = RA[3] * LN2;
}

extern "C" void kernel_launch(void* const* d_in, const int* in_sizes, int n_in,
                              void* d_out, int out_size, void* d_ws, size_t ws_size,
                              hipStream_t stream) {
  const float* x = (const float*)d_in[0];
  const float* y = (const float*)d_in[1];
  float* out = (float*)d_out;
  const int B = in_sizes[0] / (256 * 8);
  const size_t need = (size_t)B * 262144;   // 2 chains x 128 quads x 64 x 16B
  if (ws_size >= need) {
    uint4* Kp4 = (uint4*)d_ws;
    softdtw_prep<<<dim3(B * 8), dim3(256), 0, stream>>>(x, y, Kp4, B);
    softdtw_dp<<<dim3(B), dim3(64), 0, stream>>>(Kp4, out);
  } else {
    softdtw_fallback<<<dim3(B), dim3(64), 0, stream>>>(x, y, out);
  }
}

// Round 15
// 54.679 us; speedup vs baseline: 1.7396x; 1.1924x over previous
//
#include <hip/hip_runtime.h>

#ifndef __has_builtin
#define __has_builtin(x) 0
#endif

#if __has_builtin(__builtin_amdgcn_logf)
__device__ __forceinline__ float flog2(float x) { return __builtin_amdgcn_logf(x); }
#else
__device__ __forceinline__ float flog2(float x) { return log2f(x); }
#endif
#if __has_builtin(__builtin_amdgcn_exp2f)
__device__ __forceinline__ float fexp2(float x) { return __builtin_amdgcn_exp2f(x); }
#else
__device__ __forceinline__ float fexp2(float x) { return exp2f(x); }
#endif

#define L2E 1.4426950408889634f   // log2(e)
#define LN2 0.6931471805599453
#define BIGL (1.0e10f * L2E)

template <int CTRL, int RM, int BM>
__device__ __forceinline__ float dpp_f(float v, float old) {
  int r = __builtin_amdgcn_update_dpp(__builtin_bit_cast(int, old),
                                      __builtin_bit_cast(int, v),
                                      CTRL, RM, BM, false);
  return __builtin_bit_cast(float, r);
}

// lane i <- lane i-1; lane 0 <- 0. fp64 via DPP on both halves.
__device__ __forceinline__ double shup1z_d(double v) {
  int lo = __double2loint(v), hi = __double2hiint(v);
  int lo2 = __builtin_amdgcn_update_dpp(0, lo, 0x138, 0xF, 0xF, false);
  int hi2 = __builtin_amdgcn_update_dpp(0, hi, 0x138, 0xF, 0xF, false);
  return __hiloint2double(hi2, lo2);
}

// wave max -> lane 63 (nonnegative floats)
__device__ __forceinline__ float wave_max63(float m) {
  m = fmaxf(m, dpp_f<0x111, 0xF, 0xF>(m, m));  // row_shr:1
  m = fmaxf(m, dpp_f<0x112, 0xF, 0xF>(m, m));  // row_shr:2
  m = fmaxf(m, dpp_f<0x114, 0xF, 0xF>(m, m));  // row_shr:4
  m = fmaxf(m, dpp_f<0x118, 0xF, 0xF>(m, m));  // row_shr:8
  m = fmaxf(m, dpp_f<0x142, 0xA, 0xF>(m, m));  // row_bcast15 -> rows 1,3
  m = fmaxf(m, dpp_f<0x143, 0xC, 0xF>(m, m));  // row_bcast31 -> rows 2,3
  return m;
}

// ---------------- prep: K = bf16(exp(-||x_i - y_j||^2)), PAIR-major layout --
// Kp4[b*16384 + kk2*64 + tt] : 16B = lane tt's 4 cells for diag pair
// {2*kk2, 2*kk2+1}. Diag slot 511 = tileK row 63 of last block = zeros.
// (Verbatim the R9 champion prep: global y via L1, vectorized loads.)
__global__ __launch_bounds__(256) void softdtw_prep(
    const float* __restrict__ x, const float* __restrict__ y,
    uint4* __restrict__ Kp4, int B)
{
  const int b  = blockIdx.x % B;            // XCD-aligned with dp block b
  const int K0 = (blockIdx.x / B) << 6;
  const int i0 = threadIdx.x;               // 0..255

  __shared__ __align__(16) unsigned short tileK[64][256];   // [kkL][i0]

  const float* xb = x + ((size_t)b * 256 + i0) * 8;
  float4 xa = *(const float4*)(xb);
  float4 xc = *(const float4*)(xb + 4);
  const float* yb = y + (size_t)b * 256 * 8;

  for (int jj = 0; jj < 64; ++jj) {
    int j0 = K0 + jj - i0;
    bool valid = (unsigned)j0 < 256u;
    int jc = j0 < 0 ? 0 : (j0 > 255 ? 255 : j0);
    const float4* yp = (const float4*)(yb + jc * 8);
    float4 ya = yp[0], yc = yp[1];
    float d, D;
    d = xa.x - ya.x; D = d * d;
    d = xa.y - ya.y; D = fmaf(d, d, D);
    d = xa.z - ya.z; D = fmaf(d, d, D);
    d = xa.w - ya.w; D = fmaf(d, d, D);
    d = xc.x - yc.x; D = fmaf(d, d, D);
    d = xc.y - yc.y; D = fmaf(d, d, D);
    d = xc.z - yc.z; D = fmaf(d, d, D);
    d = xc.w - yc.w; D = fmaf(d, d, D);
    float K = valid ? fexp2(-L2E * D) : 0.0f;
    unsigned kb = __builtin_bit_cast(unsigned, K);
    unsigned rn = (kb + 0x7FFFu + ((kb >> 16) & 1u)) >> 16;   // RNE to bf16
    tileK[jj][i0] = (unsigned short)rn;
  }
  __syncthreads();

  const size_t obase4 = (size_t)b * 16384;
  #pragma unroll
  for (int w = 0; w < 8; ++w) {
    int p = threadIdx.x + (w << 8);
    int kkP = p >> 6;
    int tt = p & 63;
    uint2 lo = *(const uint2*)&tileK[kkP * 2][tt * 4];
    uint2 hi = *(const uint2*)&tileK[kkP * 2 + 1][tt * 4];
    uint4 v; v.x = lo.x; v.y = lo.y; v.z = hi.x; v.w = hi.y;
    Kp4[obase4 + (size_t)((K0 >> 1) + kkP) * 64 + tt] = v;
  }
}

// ---------------- DP: f64 common-scale (R9 numerics), 32-step chunks --------
// Changes vs R9 (both issue-subtractive, mantissa-exact):
//  - RENORM every 16 steps (was 8). 2^s scaling is exact => identical output.
//    Overflow: EN <= 2^800 * 3^16 = 2^841; EO <= 2^800+144+25 = 2^969 < 2^1024.
//  - 32-step chunks (16 uint4 dbuf): half the waitcnt/sched events, 2x slack.
__global__ __launch_bounds__(64) void softdtw_dp(
    const uint4* __restrict__ Kp4, float* __restrict__ out)
{
  const int b = blockIdx.x;
  const int t = threadIdx.x;

  const char* kbase = (const char*)(Kp4 + (size_t)b * 16384) + t * 16;

  double EA[4] = {0.0, 0.0, 0.0, 0.0};
  double EB[4] = {0.0, 0.0, 0.0, 0.0};
  double dgc = 0.0;          // carried: shup(diag s-2 [3]) for the next step
  int Csum = 0;

#define DPSTEP2(KAw, KBw, E2, E1, FIRSTF) do {                                \
    double K0_ = (double)__builtin_bit_cast(float, (KAw) << 16);              \
    double K1_ = (double)__builtin_bit_cast(float, (KAw) & 0xFFFF0000u);      \
    double K2_ = (double)__builtin_bit_cast(float, (KBw) << 16);              \
    double K3_ = (double)__builtin_bit_cast(float, (KBw) & 0xFFFF0000u);      \
    double up_ = shup1z_d(E1[3]);                                             \
    double dg_ = dgc;                                                         \
    if (FIRSTF) dg_ = (t == 0) ? 1.0 : dg_;                                   \
    double V0_ = K0_ * (dg_   + (up_   + E1[0]));                             \
    double V1_ = K1_ * (E2[0] + (E1[0] + E1[1]));                             \
    double V2_ = K2_ * (E2[1] + (E1[1] + E1[2]));                             \
    double V3_ = K3_ * (E2[2] + (E1[2] + E1[3]));                             \
    dgc = up_;                                                                \
    E2[0] = V0_; E2[1] = V1_; E2[2] = V2_; E2[3] = V3_;                       \
  } while (0)

#define RENORM(EN, EO) do {                                                   \
    double m4_ = fmax(fmax(EN[0], EN[1]), fmax(EN[2], EN[3]));                \
    float mh_ = __builtin_bit_cast(float, __double2hiint(m4_));               \
    mh_ = wave_max63(mh_);                                                    \
    int mb_ = __builtin_amdgcn_readlane(__builtin_bit_cast(int, mh_), 63);    \
    int s_ = (mb_ == 0) ? 0 : (1823 - ((mb_ >> 20) & 0x7FF));                 \
    EN[0] = ldexp(EN[0], s_); EN[1] = ldexp(EN[1], s_);                       \
    EN[2] = ldexp(EN[2], s_); EN[3] = ldexp(EN[3], s_);                       \
    EO[0] = ldexp(EO[0], s_); EO[1] = ldexp(EO[1], s_);                       \
    EO[2] = ldexp(EO[2], s_); EO[3] = ldexp(EO[3], s_);                       \
    dgc = ldexp(dgc, s_);                                                     \
    Csum += s_;                                                               \
  } while (0)

  // one pair (2 steps): even step writes EA, odd writes EB
#define PAIR(U, FIRSTF)                                                       \
    DPSTEP2((U).x, (U).y, EA, EB, FIRSTF);                                    \
    DPSTEP2((U).z, (U).w, EB, EA, false)

  // one 32-step chunk: issue next chunk's 16 loads, then 16 pairs from CB,
  // RENORM after pair 7 (16 steps) and pair 15 (32 steps).
#define CHUNK32(CB, LB, FIRSTF) do {                                          \
    LB[0]  = *(const uint4*)(kbase);                                          \
    LB[1]  = *(const uint4*)(kbase + 1024);                                   \
    LB[2]  = *(const uint4*)(kbase + 2048);                                   \
    LB[3]  = *(const uint4*)(kbase + 3072);                                   \
    LB[4]  = *(const uint4*)(kbase + 4096);                                   \
    LB[5]  = *(const uint4*)(kbase + 5120);                                   \
    LB[6]  = *(const uint4*)(kbase + 6144);                                   \
    LB[7]  = *(const uint4*)(kbase + 7168);                                   \
    LB[8]  = *(const uint4*)(kbase + 8192);                                   \
    LB[9]  = *(const uint4*)(kbase + 9216);                                   \
    LB[10] = *(const uint4*)(kbase + 10240);                                  \
    LB[11] = *(const uint4*)(kbase + 11264);                                  \
    LB[12] = *(const uint4*)(kbase + 12288);                                  \
    LB[13] = *(const uint4*)(kbase + 13312);                                  \
    LB[14] = *(const uint4*)(kbase + 14336);                                  \
    LB[15] = *(const uint4*)(kbase + 15360);                                  \
    kbase += 16384;                                                           \
    __builtin_amdgcn_sched_barrier(0);                                        \
    PAIR(CB[0], FIRSTF); PAIR(CB[1], false);                                  \
    PAIR(CB[2], false);  PAIR(CB[3], false);                                  \
    PAIR(CB[4], false);  PAIR(CB[5], false);                                  \
    PAIR(CB[6], false);  PAIR(CB[7], false);                                  \
    RENORM(EB, EA);                                                           \
    PAIR(CB[8], false);  PAIR(CB[9], false);                                  \
    PAIR(CB[10], false); PAIR(CB[11], false);                                 \
    PAIR(CB[12], false); PAIR(CB[13], false);                                 \
    PAIR(CB[14], false); PAIR(CB[15], false);                                 \
    RENORM(EB, EA);                                                           \
  } while (0)

  uint4 KA[16], KB[16];
  // preload chunk 0 (pairs 0..15)
  #pragma unroll
  for (int q = 0; q < 16; ++q)
    KA[q] = *(const uint4*)(kbase + q * 1024);
  kbase += 16384;

  CHUNK32(KA, KB, true);            // chunk 0 (steps 0..31), loads chunk 1
  #pragma unroll 1
  for (int c = 0; c < 7; ++c) {     // chunks 1..14 (steps 32..479)
    CHUNK32(KB, KA, false);
    CHUNK32(KA, KB, false);
  }
  // tail: steps 480..510 (31 steps) from KB (pairs 240..255), no loads
  PAIR(KB[0], false); PAIR(KB[1], false);
  PAIR(KB[2], false); PAIR(KB[3], false);
  PAIR(KB[4], false); PAIR(KB[5], false);
  PAIR(KB[6], false); PAIR(KB[7], false);
  RENORM(EB, EA);
  PAIR(KB[8], false);  PAIR(KB[9], false);
  PAIR(KB[10], false); PAIR(KB[11], false);
  PAIR(KB[12], false); PAIR(KB[13], false);
  PAIR(KB[14], false);
  DPSTEP2(KB[15].x, KB[15].y, EA, EB, false);  // step 510 -> EA, result EA[3]

  if (t == 63) {
    int ex;
    double mant = frexp(EA[3], &ex);   // mant in [0.5, 1)
    float l2 = (float)ex + flog2((float)mant);
    out[b] = (float)(LN2 * ((double)Csum - (double)l2));
  }
}

// ---------------- fallback (R1 log-domain kernel), used if ws too small -----
__global__ __launch_bounds__(64) void softdtw_fallback(
    const float* __restrict__ x, const float* __restrict__ y,
    float* __restrict__ out)
{
  const int b = blockIdx.x;
  const int t = threadIdx.x;
  __shared__ float zbuf[4][64][9];
  const float* xb = x + (size_t)b * 256 * 8;
  const float* yb = y + (size_t)b * 256 * 8;
  float xe[4][9];
  float x2L[4];
  #pragma unroll
  for (int r = 0; r < 4; ++r) {
    const int row = 4 * t + r;
    float4 a = *(const float4*)(yb + row * 8);
    float4 c = *(const float4*)(yb + row * 8 + 4);
    float y2 = a.x*a.x + a.y*a.y + a.z*a.z + a.w*a.w
             + c.x*c.x + c.y*c.y + c.z*c.z + c.w*c.w;
    float* zr = &zbuf[r][t][0];
    zr[0] = -2.0f*L2E*a.x; zr[1] = -2.0f*L2E*a.y; zr[2] = -2.0f*L2E*a.z; zr[3] = -2.0f*L2E*a.w;
    zr[4] = -2.0f*L2E*c.x; zr[5] = -2.0f*L2E*c.y; zr[6] = -2.0f*L2E*c.z; zr[7] = -2.0f*L2E*c.w;
    zr[8] = L2E * y2;
    float4 xa = *(const float4*)(xb + row * 8);
    float4 xc = *(const float4*)(xb + row * 8 + 4);
    xe[r][0]=xa.x; xe[r][1]=xa.y; xe[r][2]=xa.z; xe[r][3]=xa.w;
    xe[r][4]=xc.x; xe[r][5]=xc.y; xe[r][6]=xc.z; xe[r][7]=xc.w; xe[r][8]=1.0f;
    x2L[r] = L2E*(xa.x*xa.x + xa.y*xa.y + xa.z*xa.z + xa.w*xa.w
                + xc.x*xc.x + xc.y*xc.y + xc.z*xc.z + xc.w*xc.w);
  }
  __syncthreads();
  float zA[9], zB[9], zC[9], zD[9];
  #pragma unroll
  for (int w = 0; w < 9; ++w) { zA[w]=0.f; zB[w]=0.f; zC[w]=0.f; zD[w]=0.f; }
  float RA[4] = {BIGL,BIGL,BIGL,BIGL};
  float RB[4] = {BIGL,BIGL,BIGL,BIGL};
  int u = -4 * t;
  auto ROW = [&](int r, float a, float bb, float c, const float (&zr)[9]) -> float {
    float acc = x2L[r];
    #pragma unroll
    for (int d = 0; d < 9; ++d) acc = fmaf(xe[r][d], zr[d], acc);
    float m = fminf(fminf(a, bb), c);
    float e = fexp2(m-a) + fexp2(m-bb) + fexp2(m-c);
    float val = acc + (m - flog2(e));
    return ((unsigned)(u - r) < 256u) ? val : BIGL;
  };
  auto STEP = [&](float (&zw)[9], const float (&zx)[9], const float (&zy)[9],
                  const float (&zz)[9], float (&Rm2)[4], float (&Rm1)[4],
                  int p, int k) {
    int uc = u < 0 ? 0 : (u > 255 ? 255 : u);
    const float* zp = &zbuf[p][uc >> 2][0];
    #pragma unroll
    for (int w = 0; w < 9; ++w) zw[w] = zp[w];
    float up_in = __shfl_up(Rm1[3], 1);
    float dg_in = __shfl_up(Rm2[3], 1);
    float bval = (k == 2) ? 0.0f : BIGL;
    if (t == 0) { up_in = BIGL; dg_in = bval; }
    float n0 = ROW(0, dg_in,  up_in,  Rm1[0], zw);
    float n1 = ROW(1, Rm2[0], Rm1[0], Rm1[1], zx);
    float n2 = ROW(2, Rm2[1], Rm1[1], Rm1[2], zy);
    float n3 = ROW(3, Rm2[2], Rm1[2], Rm1[3], zz);
    Rm2[0]=n0; Rm2[1]=n1; Rm2[2]=n2; Rm2[3]=n3;
    u += 1;
  };
  int k = 2;
  for (int mi = 0; mi < 127; ++mi) {
    STEP(zD, zA, zB, zC, RA, RB, 0, k);
    STEP(zC, zD, zA, zB, RB, RA, 1, k + 1);
    STEP(zB, zC, zD, zA, RA, RB, 2, k + 2);
    STEP(zA, zB, zC, zD, RB, RA, 3, k + 3);
    k += 4;
  }
  STEP(zD, zA, zB, zC, RA, RB, 0, k);
  STEP(zC, zD, zA, zB, RB, RA, 1, k + 1);
  STEP(zB, zC, zD, zA, RA, RB, 2, k + 2);
  if (t == 63) out[b] = RA[3] * LN2;
}

extern "C" void kernel_launch(void* const* d_in, const int* in_sizes, int n_in,
                              void* d_out, int out_size, void* d_ws, size_t ws_size,
                              hipStream_t stream) {
  const float* x = (const float*)d_in[0];
  const float* y = (const float*)d_in[1];
  float* out = (float*)d_out;
  const int B = in_sizes[0] / (256 * 8);
  const size_t need = (size_t)B * 262144;   // 256 diag-pairs x 64 lanes x 16B
  if (ws_size >= need) {
    uint4* Kp4 = (uint4*)d_ws;
    softdtw_prep<<<dim3(B * 8), dim3(256), 0, stream>>>(x, y, Kp4, B);
    softdtw_dp<<<dim3(B), dim3(64), 0, stream>>>(Kp4, out);
  } else {
    softdtw_fallback<<<dim3(B), dim3(64), 0, stream>>>(x, y, out);
  }
}